// Round 5
// baseline (141.350 us; speedup 1.0000x reference)
//
#include <hip/hip_runtime.h>

typedef unsigned short u16;
typedef unsigned int u32;

typedef __bf16 bf16x8 __attribute__((ext_vector_type(8)));
typedef float f32x4 __attribute__((ext_vector_type(4)));

#define OUT_F 4096
#define IN_F 4096
#define M_ROWS 4096              // 2 * 2048
#define NUM_GROUPS ((OUT_F * IN_F) / 32)   // 524288

#define TILE_E (256 * 64)        // u16 elements per LDS tile buffer (32 KB)

// ---------- helpers ----------

__device__ __forceinline__ u16 f2bf(float f) {
    union { float f; u32 u; } c; c.f = f;
    u32 u = c.u;
    u += 0x7fffu + ((u >> 16) & 1u);   // round-to-nearest-even (finite inputs)
    return (u16)(u >> 16);
}

__device__ __forceinline__ u32 pk2(float a, float b) {
    return (u32)f2bf(a) | ((u32)f2bf(b) << 16);
}

// async global -> LDS, 16 bytes per lane (global_load_lds_dwordx4)
__device__ __forceinline__ void async_copy16(const u16* g, u16* l) {
    __builtin_amdgcn_global_load_lds(
        (const __attribute__((address_space(1))) u32*)g,
        (__attribute__((address_space(3))) u32*)l,
        16, 0, 0);
}

// 32-bit LDS byte address for inline-asm ds_read
__device__ __forceinline__ u32 lds_addr(const u16* p) {
    return (u32)(uintptr_t)(const __attribute__((address_space(3))) u16*)p;
}

// ---------- fused prep (unchanged — not the bottleneck) ----------
__global__ __launch_bounds__(256) void prep_kernel(
        const float* __restrict__ x, const int* __restrict__ q,
        const float* __restrict__ scales,
        u16* __restrict__ W, u16* __restrict__ Xb) {
    int bid = blockIdx.x;
    int tid = threadIdx.x;
    if (bid < 8192) {
        int t = bid * 256 + tid;                 // [0, NUM_TRIPLETS)
        int b0 = q[3 * t];
        int b1 = q[3 * t + 1];
        int b2 = q[3 * t + 2];
        float mv = scales[t >> 2];
        float s = mv * (2.0f / 7.0f);            // w = v*s - mv
        float o = -mv;

        int v0 = b0 & 7;
        int v1 = (b0 >> 3) & 7;
        int v2 = ((b0 >> 6) & 3) | ((b1 & 1) << 2);
        int v3 = (b1 >> 1) & 7;
        int v4 = (b1 >> 4) & 7;
        int v5 = ((b1 >> 7) & 1) | ((b2 & 3) << 1);
        int v6 = (b2 >> 2) & 7;
        int v7 = (b2 >> 5) & 7;
        uint4 w;
        w.x = pk2(fmaf((float)v0, s, o), fmaf((float)v1, s, o));
        w.y = pk2(fmaf((float)v2, s, o), fmaf((float)v3, s, o));
        w.z = pk2(fmaf((float)v4, s, o), fmaf((float)v5, s, o));
        w.w = pk2(fmaf((float)v6, s, o), fmaf((float)v7, s, o));
        ((uint4*)W)[t] = w;
    } else {
        int i = (bid - 8192) * 256 + tid;
        const float4* p = (const float4*)x + (size_t)i * 2;
        float4 u = p[0], v = p[1];
        uint4 w;
        w.x = pk2(u.x, u.y);
        w.y = pk2(u.z, u.w);
        w.z = pk2(v.x, v.y);
        w.w = pk2(v.z, v.w);
        ((uint4*)Xb)[i] = w;
    }
}

// ---------- 256x256 single-barrier-per-tile bf16 GEMM ----------
// C[m][n] = sum_k A[m][k]*B[n][k] + bias[n]
//
// R4 post-mortem: 4384 cyc/tile = 2483 (MFMA) + ~1900 un-overlapped LDS port.
// Reads were distributed 16/0/8/0 across barrier-locked phases, so P0 was a
// pure port burst and P1/P3 pure MFMA. R5: ONE barrier per K-tile.
// Hazard ledger: within tile t, ALL 24 ds_reads hit buf(t); ALL stage-writes
// (for tile t+1) hit buf(t^1) — disjoint. Cross-tile:
//   - residency: S(t+1) issued at tile-t start, own-wave vmcnt(0) at tile end
//     (~2500 cyc later, HBM lat ~900 hidden), then s_barrier publishes to all.
//   - WAR: buf(t^1)'s last reads were tile t-1's, completed before the t-1/t
//     barrier (final wait chain ends lgkmcnt(0)); stages issue after it.
// In-wave: avA1 reads reuse av[] registers (A0 lifetime ends at Q1's last
// MFMA; in-order issue makes the WAR safe). Counted lgkm waits let reads and
// stage LDS-writes drain continuously under the 64-MFMA stream:
// per-tile ceiling ~= max(2483 MFMA, 2304 rd + 512 wr port) ~= 2850 cyc.
__global__ __launch_bounds__(512, 2) void gemm_bt_kernel(
        const u16* __restrict__ A, const u16* __restrict__ B,
        const float* __restrict__ bias, float* __restrict__ C) {
    __shared__ u16 sA[2 * TILE_E];
    __shared__ u16 sB[2 * TILE_E];

    const int tid = threadIdx.x;
    const int lane = tid & 63;
    const int w = tid >> 6;          // wave 0..7
    const int wr = w >> 2;           // wave row 0..1
    const int wc = w & 3;            // wave col 0..3
    const int ln = lane & 15;
    const int quad = lane >> 4;
    const int lnx = ln & 7;

    // XCD-aware bijective swizzle: 256 blocks, 8 XCDs, 32 contiguous tiles/XCD
    const int lin = blockIdx.x;
    const int wg = (lin & 7) * 32 + (lin >> 3);
    const int mb = (wg >> 4) * 256;   // M tile
    const int nb = (wg & 15) * 256;   // N tile

    // staging geometry: half-tile = 128 rows x 64 bf16 = 2 x 512thr x 16B
    int offg[2], offl[2];
#pragma unroll
    for (int p = 0; p < 2; ++p) {
        int s = p * 512 + tid;
        int rl = s >> 3, pc = s & 7;
        int lc = pc ^ (rl & 7);          // XOR swizzle on global source
        offg[p] = rl * IN_F + lc * 8;
        offl[p] = rl * 64 + pc * 8;      // lane-contiguous LDS dest
    }
    const u16* baseA = A + (size_t)mb * IN_F;
    const u16* baseB = B + (size_t)nb * IN_F;

    auto STAGE = [&](u16* lbase, const u16* gbase, int ko, int h) {
#pragma unroll
        for (int p = 0; p < 2; ++p)
            async_copy16(gbase + h * (128 * IN_F) + offg[p] + ko,
                         lbase + h * (128 * 64) + offl[p]);
    };

    // ds_read base addresses (bytes). Fragment byte offset decomposition:
    //   A: mh*16384 + wr*8192 + i*2048 + ln*128 + ((kk*4+quad)^lnx)*16
    //   B: nh*16384 + wc*4096 + j*2048 + ln*128 + ((kk*4+quad)^lnx)*16
    // mh/nh and i/j terms go in the ds_read offset: immediate; kk picks base.
    const u32 sAb = lds_addr(sA);
    const u32 sBb = lds_addr(sB);
    const u32 aB0 = sAb + (u32)(wr * 8192 + ln * 128 + ((quad ^ lnx) * 16));
    const u32 aB1 = sAb + (u32)(wr * 8192 + ln * 128 + (((4 + quad) ^ lnx) * 16));
    const u32 bB0 = sBb + (u32)(wc * 4096 + ln * 128 + ((quad ^ lnx) * 16));
    const u32 bB1 = sBb + (u32)(wc * 4096 + ln * 128 + (((4 + quad) ^ lnx) * 16));

    // bias for this thread's 4 output column groups
    float bj[2][2];
#pragma unroll
    for (int nh = 0; nh < 2; ++nh)
#pragma unroll
        for (int j = 0; j < 2; ++j)
            bj[nh][j] = bias[nb + nh * 128 + wc * 32 + j * 16 + ln];

    f32x4 acc[8][4];
#pragma unroll
    for (int i = 0; i < 8; ++i)
#pragma unroll
        for (int j = 0; j < 4; ++j) acc[i][j] = (f32x4)0.0f;

    bf16x8 av[4][2];      // A fragments: A0 during Q0/Q1, A1 during Q2/Q3
    bf16x8 bv0[2][2];     // B0 fragments, live whole tile (Q0 and Q3)
    bf16x8 bv1[2][2];     // B1 fragments, live Q1..Q2

#define DSR(dst, base, IMM) \
    asm volatile("ds_read_b128 %0, %1 offset:" #IMM \
                 : "=v"(dst) : "v"(base))

#define WAITG(N) \
    asm volatile("s_waitcnt lgkmcnt(" #N ")"); \
    __builtin_amdgcn_sched_barrier(0);

// 4 MFMAs: av[AI] x BV -> acc[ACR][J0], acc[ACR][J1]
#define MG(AI, ACR, J0, J1, BV) \
    acc[ACR][J0] = __builtin_amdgcn_mfma_f32_16x16x32_bf16( \
        av[AI][0], BV[0][0], acc[ACR][J0], 0, 0, 0); \
    acc[ACR][J0] = __builtin_amdgcn_mfma_f32_16x16x32_bf16( \
        av[AI][1], BV[0][1], acc[ACR][J0], 0, 0, 0); \
    acc[ACR][J1] = __builtin_amdgcn_mfma_f32_16x16x32_bf16( \
        av[AI][0], BV[1][0], acc[ACR][J1], 0, 0, 0); \
    acc[ACR][J1] = __builtin_amdgcn_mfma_f32_16x16x32_bf16( \
        av[AI][1], BV[1][1], acc[ACR][J1], 0, 0, 0);

    // ---- prologue: stage tile 0 into buf0, drain, publish ----
    STAGE(sA, baseA, 0, 0);
    STAGE(sA, baseA, 0, 1);
    STAGE(sB, baseB, 0, 0);
    STAGE(sB, baseB, 0, 1);
    asm volatile("s_waitcnt vmcnt(0)");
    __builtin_amdgcn_s_barrier();

#pragma unroll 1
    for (int t = 0; t < 64; ++t) {
        const int cur = t & 1;
        const u32 curOff = (u32)cur << 15;       // cur * 32768 B = TILE_E*2
        const u32 aC0 = aB0 + curOff, aC1 = aB1 + curOff;
        const u32 bC0 = bB0 + curOff, bC1 = bB1 + curOff;
        u16* aNx = sA + (cur ^ 1) * TILE_E;
        u16* bNx = sB + (cur ^ 1) * TILE_E;
        const int ko1 = ((t + 1) & 63) << 6;

        // ---- issue reads r1..r16: bv0(4), avA0(8), bv1(4) ----
        DSR(bv0[0][0], bC0, 0);      DSR(bv0[0][1], bC1, 0);
        DSR(bv0[1][0], bC0, 2048);   DSR(bv0[1][1], bC1, 2048);
        DSR(av[0][0], aC0, 0);       DSR(av[0][1], aC1, 0);
        DSR(av[1][0], aC0, 2048);    DSR(av[1][1], aC1, 2048);
        DSR(av[2][0], aC0, 4096);    DSR(av[2][1], aC1, 4096);
        DSR(av[3][0], aC0, 6144);    DSR(av[3][1], aC1, 6144);
        DSR(bv1[0][0], bC0, 16384);  DSR(bv1[0][1], bC1, 16384);
        DSR(bv1[1][0], bC0, 18432);  DSR(bv1[1][1], bC1, 18432);

        // ---- issue all stages for tile t+1 into buf^1 ----
        STAGE(aNx, baseA, ko1, 0);
        STAGE(aNx, baseA, ko1, 1);
        STAGE(bNx, baseB, ko1, 0);
        STAGE(bNx, baseB, ko1, 1);
        __builtin_amdgcn_sched_barrier(0);

        // ---- Q0 (A0,B0) + Q1 (A0,B1), counted waits ----
        __builtin_amdgcn_s_setprio(1);
        WAITG(10); MG(0, 0, 0, 1, bv0);
        WAITG(8);  MG(1, 1, 0, 1, bv0);
        WAITG(6);  MG(2, 2, 0, 1, bv0);
        WAITG(4);  MG(3, 3, 0, 1, bv0);
        WAITG(0);
        MG(0, 0, 2, 3, bv1);
        MG(1, 1, 2, 3, bv1);
        MG(2, 2, 2, 3, bv1);
        MG(3, 3, 2, 3, bv1);
        __builtin_amdgcn_sched_barrier(0);
        __builtin_amdgcn_s_setprio(0);

        // ---- issue reads r17..r24: avA1 (register-aliased with avA0) ----
        DSR(av[0][0], aC0, 16384);   DSR(av[0][1], aC1, 16384);
        DSR(av[1][0], aC0, 18432);   DSR(av[1][1], aC1, 18432);
        DSR(av[2][0], aC0, 20480);   DSR(av[2][1], aC1, 20480);
        DSR(av[3][0], aC0, 22528);   DSR(av[3][1], aC1, 22528);

        // ---- Q2 (A1,B1) + Q3 (A1,B0) ----
        __builtin_amdgcn_s_setprio(1);
        WAITG(6); MG(0, 4, 2, 3, bv1);
        WAITG(4); MG(1, 5, 2, 3, bv1);
        WAITG(2); MG(2, 6, 2, 3, bv1);
        WAITG(0); MG(3, 7, 2, 3, bv1);
        MG(0, 4, 0, 1, bv0);
        MG(1, 5, 0, 1, bv0);
        MG(2, 6, 0, 1, bv0);
        MG(3, 7, 0, 1, bv0);
        __builtin_amdgcn_sched_barrier(0);
        __builtin_amdgcn_s_setprio(0);

        // ---- tile boundary: own stages complete, publish to block ----
        asm volatile("s_waitcnt vmcnt(0)");
        __builtin_amdgcn_s_barrier();
    }

#undef DSR
#undef WAITG
#undef MG

    // drain trailing (wrapped t=64) prefetches before epilogue
    asm volatile("s_waitcnt vmcnt(0)");

    // ---- epilogue: C[row][col] = acc + bias[col]
#pragma unroll
    for (int ai = 0; ai < 8; ++ai) {
        const int mh = ai >> 2, i = ai & 3;
        const int mrow = mb + mh * 128 + wr * 64 + i * 16 + quad * 4;
#pragma unroll
        for (int j4 = 0; j4 < 4; ++j4) {
            const int nh = j4 >> 1, j = j4 & 1;
            const int col = nb + nh * 128 + wc * 32 + j * 16 + ln;
            float* cp = C + (size_t)mrow * OUT_F + col;
#pragma unroll
            for (int r = 0; r < 4; ++r)
                cp[(size_t)r * OUT_F] = acc[ai][j4][r] + bj[nh][j];
        }
    }
}

extern "C" void kernel_launch(void* const* d_in, const int* in_sizes, int n_in,
                              void* d_out, int out_size, void* d_ws, size_t ws_size,
                              hipStream_t stream) {
    const float* x = (const float*)d_in[0];       // [2,2048,4096] fp32
    const int* wq = (const int*)d_in[1];          // [NUM_GROUPS*12]
    const float* wn = (const float*)d_in[2];      // [NUM_GROUPS]
    const float* bias = (const float*)d_in[3];    // [4096]
    float* out = (float*)d_out;                   // [2,2048,4096] fp32

    u16* Wb = (u16*)d_ws;                         // 32 MB
    u16* Xb = Wb + (size_t)OUT_F * IN_F;          // 32 MB

    prep_kernel<<<16384, 256, 0, stream>>>(x, wq, wn, Wb, Xb);
    gemm_bt_kernel<<<dim3(256), 512, 0, stream>>>(Xb, Wb, bias, out);
}